// Round 1
// baseline (1970.026 us; speedup 1.0000x reference)
//
#include <hip/hip_runtime.h>
#include <stdint.h>

#define FP8_MAX 448.0f
#define QEPS 1e-12f

typedef __attribute__((ext_vector_type(4))) float floatx4;

typedef const __attribute__((address_space(1))) void* gas_p;
typedef __attribute__((address_space(3))) void* las_p;

__device__ __forceinline__ void gld_lds16(const uint8_t* g, uint8_t* l) {
    __builtin_amdgcn_global_load_lds((gas_p)(const void*)g, (las_p)(void*)l, 16, 0, 0);
}

// ---------------------------------------------------------------------------
// Quantize activations x [M][K] fp32 -> xq [M][K] fp8, sx [K/128][M] fp32.
// One wave per 128-element block (2 floats/lane).
// ---------------------------------------------------------------------------
__global__ __launch_bounds__(256) void k_quant_act(
    const float* __restrict__ x, uint8_t* __restrict__ xq,
    float* __restrict__ sx, int M, int K)
{
    const int wave = threadIdx.x >> 6, lane = threadIdx.x & 63;
    const int KB = K >> 7;
    long bi = (long)blockIdx.x * 4 + wave;
    const int m = (int)(bi / KB);
    const int kb = (int)(bi % KB);
    const float* p = x + (long)m * K + (long)kb * 128 + lane * 2;
    float2 v = *(const float2*)p;
    float amax = fmaxf(fabsf(v.x), fabsf(v.y));
    #pragma unroll
    for (int off = 32; off >= 1; off >>= 1)
        amax = fmaxf(amax, __shfl_xor(amax, off));
    float ac = fmaxf(amax, QEPS);
    float rs = FP8_MAX / ac;
    if (lane == 0) sx[(long)kb * M + m] = ac / FP8_MAX;
    unsigned pk = (unsigned)__builtin_amdgcn_cvt_pk_fp8_f32(v.x * rs, v.y * rs, 0, false);
    *(unsigned short*)(xq + (long)m * K + (long)kb * 128 + lane * 2) = (unsigned short)pk;
}

// ---------------------------------------------------------------------------
// Quantize weights w [K][N] fp32 (scale along K in blocks of 128) ->
// wqT [N][K] fp8 (transposed), sw [K/128][N] fp32.
// Block: 128k x 64n tile through LDS.
// ---------------------------------------------------------------------------
__global__ __launch_bounds__(256) void k_quant_w(
    const float* __restrict__ w, uint8_t* __restrict__ wqT,
    float* __restrict__ sw, int K, int N)
{
    __shared__ float tile[128][65];
    __shared__ float red[256];
    __shared__ float rsx[64];
    const int t = threadIdx.x;
    const long n0 = (long)blockIdx.x * 64;
    const long k0 = (long)blockIdx.y * 128;
    const int n = t & 63, rb = t >> 6;
    float amax = 0.0f;
    #pragma unroll 4
    for (int r = rb; r < 128; r += 4) {
        float v = w[(k0 + r) * N + n0 + n];
        tile[r][n] = v;
        amax = fmaxf(amax, fabsf(v));
    }
    red[t] = amax;
    __syncthreads();
    if (t < 64) {
        float a = fmaxf(fmaxf(red[t], red[t + 64]), fmaxf(red[t + 128], red[t + 192]));
        float ac = fmaxf(a, QEPS);
        sw[(long)blockIdx.y * N + n0 + t] = ac / FP8_MAX;
        rsx[t] = FP8_MAX / ac;
    }
    __syncthreads();
    const int c = t & 7;
    for (int nn = t >> 3; nn < 64; nn += 32) {
        float rs = rsx[nn];
        unsigned dv[4];
        #pragma unroll
        for (int q = 0; q < 4; ++q) {
            int r = c * 16 + q * 4;
            int lo = __builtin_amdgcn_cvt_pk_fp8_f32(tile[r][nn] * rs, tile[r + 1][nn] * rs, 0, false);
            dv[q] = (unsigned)__builtin_amdgcn_cvt_pk_fp8_f32(tile[r + 2][nn] * rs, tile[r + 3][nn] * rs, lo, true);
        }
        *(uint4*)(wqT + (n0 + nn) * K + k0 + c * 16) = make_uint4(dv[0], dv[1], dv[2], dv[3]);
    }
}

__device__ __forceinline__ float gelu_f(float x) {
    // 0.5*x*(1+tanh(sqrt(2/pi)*(x+0.044715 x^3))) == x*sigmoid(2*sqrt(2/pi)*(x+0.044715 x^3))
    float u2 = 1.5957691216057308f * x * fmaf(0.044715f, x * x, 1.0f);
    float e = __expf(-u2);
    return x * __builtin_amdgcn_rcpf(1.0f + e);
}

// ---------------------------------------------------------------------------
// Blockwise-fp8 GEMM: C = (Aq*sA) x (Bq*sB)^T + bias.
// Aq [M][K] fp8, sA [K/128][M]; Bq [N][K] fp8 (B transposed), sB [K/128][N].
// FUSE=true: out = fp8-quantized gelu(C) -> outQ [M][N] fp8 + outS [N/128][M].
// FUSE=false: outF [M][N] fp32 = C.
// 128x128 tile, BK=128 (one scale block), 4 waves, mfma_f32_16x16x32_fp8_fp8.
// LDS tiles are stored with a 16B-chunk XOR swizzle: chunk p = g ^ (row&7),
// realized by permuting the GLOBAL source chunk each lane fetches (LDS dest of
// global_load_lds is fixed lane*16). Fragment ds_read_b64 then hits the
// 4-cycle (512B/128B) LDS floor instead of a 16-way bank conflict.
// ---------------------------------------------------------------------------
template <bool FUSE>
__global__ __launch_bounds__(256, 2) void k_gemm_fp8(
    const uint8_t* __restrict__ Aq, const float* __restrict__ sA,
    const uint8_t* __restrict__ Bq, const float* __restrict__ sB,
    const float* __restrict__ bias,
    float* __restrict__ outF,
    uint8_t* __restrict__ outQ, float* __restrict__ outS,
    int M, int N, int K)
{
    __shared__ uint8_t sm[35328];
    uint8_t* ldsA = sm;                       // 16 KiB [128 rows][128 k]
    uint8_t* ldsB = sm + 16384;               // 16 KiB
    float* lds_sa = (float*)(sm + 32768);     // [128]
    float* lds_sb = (float*)(sm + 33280);     // [128]
    float* lds_rm = (float*)(sm + 33792);     // [2][128] row-amax (FUSE)
    float* lds_rs = (float*)(sm + 34816);     // [128]    row-rscale (FUSE)

    const int tid = threadIdx.x;
    const int wave = tid >> 6, lane = tid & 63;
    const int quad = lane >> 4, col0 = lane & 15;
    const int wm = wave >> 1, wn = wave & 1;
    const long m0 = (long)blockIdx.y * 128;
    const long n0 = (long)blockIdx.x * 128;
    const int KB = K >> 7;

    // staging: issue t covers rows wave*32 + t*8 + (lane>>3); lane fetches the
    // swizzled source 16B-chunk g = (lane&7) ^ (row&7)  (row&7 == lane>>3 here)
    const int srow = lane >> 3;
    const int g16 = ((lane & 7) ^ srow) * 16;
    const uint8_t* Ag = Aq + (m0 + wave * 32 + srow) * K + g16;
    const uint8_t* Bg = Bq + (n0 + wave * 32 + srow) * K + g16;
    uint8_t* ldsAw = ldsA + wave * 32 * 128;
    uint8_t* ldsBw = ldsB + wave * 32 * 128;

    const int x7 = col0 & 7;
    const int cb = quad >> 1;
    const int oddoff = (quad & 1) * 8;

    int arow[4], brow[4];
    #pragma unroll
    for (int i = 0; i < 4; ++i) {
        arow[i] = (wm * 64 + i * 16 + col0) * 128;
        brow[i] = (wn * 64 + i * 16 + col0) * 128;
    }

    const floatx4 z4 = {0.0f, 0.0f, 0.0f, 0.0f};
    floatx4 master[4][4];
    #pragma unroll
    for (int mi = 0; mi < 4; ++mi)
        #pragma unroll
        for (int ni = 0; ni < 4; ++ni)
            master[mi][ni] = z4;

    for (int kb = 0; kb < KB; ++kb) {
        // stage per-k-block scales (coalesced 512B each)
        if (tid < 128)
            lds_sa[tid] = sA[(long)kb * M + m0 + tid];
        else
            lds_sb[tid - 128] = sB[(long)kb * N + n0 + (tid - 128)];
        // stage fp8 tiles: 4+4 global_load_lds_dwordx4 issues per wave
        const uint8_t* Agk = Ag + (long)kb * 128;
        const uint8_t* Bgk = Bg + (long)kb * 128;
        #pragma unroll
        for (int t = 0; t < 4; ++t) {
            gld_lds16(Agk + (long)t * 8 * K, ldsAw + t * 1024);
            gld_lds16(Bgk + (long)t * 8 * K, ldsBw + t * 1024);
        }
        __syncthreads();

        floatx4 part[4][4];
        #pragma unroll
        for (int ks = 0; ks < 4; ++ks) {
            const int ch = ((ks * 2 + cb) ^ x7) * 16 + oddoff;
            long af[4], bf[4];
            #pragma unroll
            for (int i = 0; i < 4; ++i) {
                af[i] = *(const long*)(ldsA + arow[i] + ch);
                bf[i] = *(const long*)(ldsB + brow[i] + ch);
            }
            #pragma unroll
            for (int mi = 0; mi < 4; ++mi)
                #pragma unroll
                for (int ni = 0; ni < 4; ++ni)
                    part[mi][ni] = __builtin_amdgcn_mfma_f32_16x16x32_fp8_fp8(
                        af[mi], bf[ni], ks == 0 ? z4 : part[mi][ni], 0, 0, 0);
        }

        // rescale partials by sA[row]*sB[col] and accumulate
        float4 sa4[4];
        float sb4[4];
        #pragma unroll
        for (int mi = 0; mi < 4; ++mi)
            sa4[mi] = *(const float4*)&lds_sa[wm * 64 + mi * 16 + quad * 4];
        #pragma unroll
        for (int ni = 0; ni < 4; ++ni)
            sb4[ni] = lds_sb[wn * 64 + ni * 16 + col0];
        #pragma unroll
        for (int mi = 0; mi < 4; ++mi) {
            floatx4 sav = {sa4[mi].x, sa4[mi].y, sa4[mi].z, sa4[mi].w};
            #pragma unroll
            for (int ni = 0; ni < 4; ++ni)
                master[mi][ni] += (part[mi][ni] * sav) * sb4[ni];
        }
        __syncthreads();
    }

    float bcol[4];
    #pragma unroll
    for (int ni = 0; ni < 4; ++ni)
        bcol[ni] = bias[n0 + wn * 64 + ni * 16 + col0];

    if (FUSE) {
        // bias + gelu in-place; per-row amax over this wave's 64 cols
        float rmax[4][4];
        #pragma unroll
        for (int mi = 0; mi < 4; ++mi)
            #pragma unroll
            for (int r = 0; r < 4; ++r) {
                float am = 0.0f;
                #pragma unroll
                for (int ni = 0; ni < 4; ++ni) {
                    float g = gelu_f(master[mi][ni][r] + bcol[ni]);
                    master[mi][ni][r] = g;
                    am = fmaxf(am, fabsf(g));
                }
                rmax[mi][r] = am;
            }
        #pragma unroll
        for (int off = 1; off < 16; off <<= 1)
            #pragma unroll
            for (int mi = 0; mi < 4; ++mi)
                #pragma unroll
                for (int r = 0; r < 4; ++r)
                    rmax[mi][r] = fmaxf(rmax[mi][r], __shfl_xor(rmax[mi][r], off));
        if (col0 == 0) {
            #pragma unroll
            for (int mi = 0; mi < 4; ++mi)
                #pragma unroll
                for (int r = 0; r < 4; ++r)
                    lds_rm[wn * 128 + wm * 64 + mi * 16 + quad * 4 + r] = rmax[mi][r];
        }
        __syncthreads();
        if (tid < 128) {
            float a = fmaxf(lds_rm[tid], lds_rm[128 + tid]);
            float ac = fmaxf(a, QEPS);
            outS[(n0 >> 7) * M + m0 + tid] = ac / FP8_MAX;
            lds_rs[tid] = FP8_MAX / ac;
        }
        __syncthreads();
        // quantize to fp8, pack via LDS (reuse ldsA) for coalesced stores
        #pragma unroll
        for (int mi = 0; mi < 4; ++mi)
            #pragma unroll
            for (int r = 0; r < 4; ++r) {
                int lrow = wm * 64 + mi * 16 + quad * 4 + r;
                float rs = lds_rs[lrow];
                #pragma unroll
                for (int ni = 0; ni < 4; ++ni) {
                    unsigned b = (unsigned)__builtin_amdgcn_cvt_pk_fp8_f32(
                                     master[mi][ni][r] * rs, 0.0f, 0, false) & 0xffu;
                    ldsA[lrow * 128 + wn * 64 + ni * 16 + col0] = (uint8_t)b;
                }
            }
        __syncthreads();
        #pragma unroll
        for (int i = 0; i < 4; ++i) {
            int cch = tid + i * 256;
            int row = cch >> 3, coff = (cch & 7) * 16;
            uint4 v = *(const uint4*)(ldsA + cch * 16);
            *(uint4*)(outQ + (m0 + row) * N + n0 + coff) = v;
        }
    } else {
        #pragma unroll
        for (int mi = 0; mi < 4; ++mi)
            #pragma unroll
            for (int r = 0; r < 4; ++r) {
                long grow = m0 + wm * 64 + mi * 16 + quad * 4 + r;
                #pragma unroll
                for (int ni = 0; ni < 4; ++ni)
                    outF[grow * N + n0 + wn * 64 + ni * 16 + col0] =
                        master[mi][ni][r] + bcol[ni];
            }
    }
}

extern "C" void kernel_launch(void* const* d_in, const int* in_sizes, int n_in,
                              void* d_out, int out_size, void* d_ws, size_t ws_size,
                              hipStream_t stream)
{
    (void)n_in; (void)out_size; (void)ws_size;
    const float* x  = (const float*)d_in[0];
    const float* w1 = (const float*)d_in[1];
    const float* b1 = (const float*)d_in[2];
    const float* w2 = (const float*)d_in[3];
    const float* b2 = (const float*)d_in[4];
    float* out = (float*)d_out;

    const int N1 = in_sizes[2];       // 8192
    const int K1 = in_sizes[1] / N1;  // 2048
    const int M  = in_sizes[0] / K1;  // 8192
    const int N2 = in_sizes[4];       // 8192
    const int K2 = in_sizes[3] / N2;  // 8192 (= N1)

    uint8_t* p = (uint8_t*)d_ws;
    uint8_t* xq  = p; p += (size_t)M * K1;
    uint8_t* w1q = p; p += (size_t)N1 * K1;
    uint8_t* hq  = p; p += (size_t)M * N1;
    uint8_t* w2q = p; p += (size_t)N2 * K2;
    float* sx  = (float*)p; p += (size_t)(K1 / 128) * M * 4;
    float* sw1 = (float*)p; p += (size_t)(K1 / 128) * N1 * 4;
    float* sh  = (float*)p; p += (size_t)(K2 / 128) * M * 4;
    float* sw2 = (float*)p; p += (size_t)(K2 / 128) * N2 * 4;

    k_quant_act<<<dim3(M * (K1 / 128) / 4), dim3(256), 0, stream>>>(x, xq, sx, M, K1);
    k_quant_w<<<dim3(N1 / 64, K1 / 128), dim3(256), 0, stream>>>(w1, w1q, sw1, K1, N1);
    k_quant_w<<<dim3(N2 / 64, K2 / 128), dim3(256), 0, stream>>>(w2, w2q, sw2, K2, N2);
    k_gemm_fp8<true><<<dim3(N1 / 128, M / 128), dim3(256), 0, stream>>>(
        xq, sx, w1q, sw1, b1, (float*)nullptr, hq, sh, M, N1, K1);
    k_gemm_fp8<false><<<dim3(N2 / 128, M / 128), dim3(256), 0, stream>>>(
        hq, sh, w2q, sw2, b2, out, (uint8_t*)nullptr, (float*)nullptr, M, N2, K2);
}